// Round 1
// baseline (2214.168 us; speedup 1.0000x reference)
//
#include <hip/hip_runtime.h>
#include <hip/hip_bf16.h>

typedef __hip_bfloat16 bf16;
typedef short bf16x8 __attribute__((ext_vector_type(8)));
typedef float f32x4 __attribute__((ext_vector_type(4)));

#define DEVINL __device__ __forceinline__

DEVINL float gelu_f(float x) { return 0.5f * x * (1.0f + erff(x * 0.7071067811865475f)); }

DEVINL void gload_lds16(const void* g, void* l) {
  __builtin_amdgcn_global_load_lds((const __attribute__((address_space(1))) int*)g,
                                   (__attribute__((address_space(3))) int*)l, 16, 0, 0);
}

DEVINL unsigned pack2bf(float a, float b) {
  union { bf16 h; unsigned short u; } ca, cb;
  ca.h = __float2bfloat16(a); cb.h = __float2bfloat16(b);
  return (unsigned)ca.u | ((unsigned)cb.u << 16);
}

// ---------------------------------------------------------------- GEMM
// C[M,N] = A[M,K](bf16,row-major) * Bt[N,K](bf16,row-major)^T (+bias[col]) (gelu?) (+resid) -> OT
template<int BM, int BN, bool GELU_, bool TROUT, bool HBIAS, bool HRES, typename OT>
__global__ __launch_bounds__(256)
void gemm_bt(const bf16* __restrict__ A, const bf16* __restrict__ Bt,
             OT* __restrict__ out, const float* __restrict__ bias,
             const float* __restrict__ resid,
             int M, int N, int K, long sA, long sO, int ldo)
{
  constexpr int BK = 32;
  __shared__ bf16 As[BM * BK];
  __shared__ bf16 Bs[BN * BK];
  const int z = blockIdx.z;
  A += z * sA; out += z * sO;
  if (HRES) resid += z * sO;
  const int n0 = blockIdx.x * BN;
  const int m0 = blockIdx.y * BM;
  const int t = threadIdx.x;
  const int lane = t & 63;
  const int wid = t >> 6;
  const int q = lane >> 4, l15 = lane & 15;
  constexpr int WM = BM / 2, WN = BN / 2;
  const int wm = (wid >> 1) * WM, wn = (wid & 1) * WN;
  constexpr int MR = WM / 16, NR = WN / 16;
  f32x4 acc[MR][NR] = {};

  constexpr int ACH = (BM * BK * 2) / (256 * 16);
  constexpr int BCH = (BN * BK * 2) / (256 * 16);

  for (int k0 = 0; k0 < K; k0 += BK) {
    __syncthreads();
#pragma unroll
    for (int i = 0; i < ACH; i++) {
      int c16 = i * 256 + t;
      int row = c16 >> 2, ko = (c16 & 3) * 8;
      gload_lds16(A + (long)(m0 + row) * K + k0 + ko, (char*)As + c16 * 16);
    }
#pragma unroll
    for (int i = 0; i < BCH; i++) {
      int c16 = i * 256 + t;
      int row = c16 >> 2, ko = (c16 & 3) * 8;
      gload_lds16(Bt + (long)(n0 + row) * K + k0 + ko, (char*)Bs + c16 * 16);
    }
    __syncthreads();
    bf16x8 af[MR], bfr[NR];
#pragma unroll
    for (int mr = 0; mr < MR; mr++) af[mr] = *(const bf16x8*)(As + (wm + mr * 16 + l15) * BK + q * 8);
#pragma unroll
    for (int nr = 0; nr < NR; nr++) bfr[nr] = *(const bf16x8*)(Bs + (wn + nr * 16 + l15) * BK + q * 8);
#pragma unroll
    for (int mr = 0; mr < MR; mr++)
#pragma unroll
      for (int nr = 0; nr < NR; nr++)
        acc[mr][nr] = __builtin_amdgcn_mfma_f32_16x16x32_bf16(af[mr], bfr[nr], acc[mr][nr], 0, 0, 0);
  }
#pragma unroll
  for (int mr = 0; mr < MR; mr++)
#pragma unroll
    for (int nr = 0; nr < NR; nr++)
#pragma unroll
      for (int r = 0; r < 4; r++) {
        int row = m0 + wm + mr * 16 + q * 4 + r;
        int col = n0 + wn + nr * 16 + l15;
        float v = acc[mr][nr][r];
        if (HBIAS) v += bias[col];
        if (GELU_) v = gelu_f(v);
        long oi = TROUT ? (long)col * ldo + row : (long)row * ldo + col;
        if (HRES) v += resid[oi];
        if constexpr (sizeof(OT) == 2) out[oi] = __float2bfloat16(v);
        else out[oi] = v;
      }
}

// ---------------------------------------------------------------- LayerNorm (C=768)
DEVINL float block_red_sum(float v, float* sbuf) {
#pragma unroll
  for (int off = 32; off; off >>= 1) v += __shfl_xor(v, off, 64);
  int wid = threadIdx.x >> 6;
  __syncthreads();
  if ((threadIdx.x & 63) == 0) sbuf[wid] = v;
  __syncthreads();
  return sbuf[0] + sbuf[1] + sbuf[2] + sbuf[3];
}

template<bool WF, bool WB>
__global__ __launch_bounds__(256)
void ln768(const float* __restrict__ in, const float* __restrict__ gw,
           const float* __restrict__ bw, float* __restrict__ of, bf16* __restrict__ ob)
{
  __shared__ float sbuf[4];
  const long row = blockIdx.x;
  const float* r = in + row * 768;
  const int t = threadIdx.x;
  float v0 = r[t], v1 = r[t + 256], v2 = r[t + 512];
  float s = block_red_sum(v0 + v1 + v2, sbuf);
  float mean = s * (1.0f / 768.0f);
  float d0 = v0 - mean, d1 = v1 - mean, d2 = v2 - mean;
  float ss = block_red_sum(d0 * d0 + d1 * d1 + d2 * d2, sbuf);
  float rstd = 1.0f / sqrtf(ss * (1.0f / 768.0f) + 1e-5f);
  float o0 = d0 * rstd * gw[t] + bw[t];
  float o1 = d1 * rstd * gw[t + 256] + bw[t + 256];
  float o2 = d2 * rstd * gw[t + 512] + bw[t + 512];
  long base = row * 768;
  if (WF) { of[base + t] = o0; of[base + t + 256] = o1; of[base + t + 512] = o2; }
  if (WB) {
    ob[base + t] = __float2bfloat16(o0);
    ob[base + t + 256] = __float2bfloat16(o1);
    ob[base + t + 512] = __float2bfloat16(o2);
  }
}

// ---------------------------------------------------------------- transpose + cast f32[K,N] -> bf16[N,K]
DEVINL void tile_tc(const float* __restrict__ src, bf16* __restrict__ dst, int K, int N, int k0, int n0) {
  __shared__ float tl[64][65];
  int t = threadIdx.x;
  int c = t & 63, r0 = t >> 6;
#pragma unroll
  for (int i = 0; i < 16; i++) {
    int r = r0 * 16 + i;
    tl[r][c] = src[(long)(k0 + r) * N + n0 + c];
  }
  __syncthreads();
#pragma unroll
  for (int i = 0; i < 16; i++) {
    int n = r0 * 16 + i;
    dst[(long)(n0 + n) * K + k0 + c] = __float2bfloat16(tl[c][n]);
  }
}

struct TDesc { const float* src; bf16* dst; int K; int N; };
struct TTab { TDesc d[14]; };

__global__ __launch_bounds__(256) void transpose_many(TTab tab) {
  int bid = blockIdx.x;
  int i = 0, base = 0;
  for (i = 0; i < 14; i++) {
    int nt = (tab.d[i].K >> 6) * (tab.d[i].N >> 6);
    if (bid < base + nt) break;
    base += nt;
  }
  TDesc de = tab.d[i];
  int local = bid - base, ntx = de.N >> 6;
  tile_tc(de.src, de.dst, de.K, de.N, (local / ntx) * 64, (local % ntx) * 64);
}

__global__ __launch_bounds__(256) void transpose_batched(const float* __restrict__ src, bf16* __restrict__ dst,
                                                         int K, int N, long sS, long sD) {
  tile_tc(src + blockIdx.z * sS, dst + blockIdx.z * sD, K, N, blockIdx.y * 64, blockIdx.x * 64);
}

__global__ void concat_bias(const float* a, const float* b, const float* c, const float* d, float* o) {
  int i = blockIdx.x * 256 + threadIdx.x;
  float v;
  if (i < 768) v = a[i];
  else if (i < 1536) v = b[i - 768];
  else if (i < 2304) v = c[i - 1536];
  else v = d[i - 2304];
  o[i] = v;
}

// ---------------------------------------------------------------- flash cross-attention
// grid: B*H blocks; Q tile 64x64 (wave w owns g in [16w,16w+16)); streams K/V in 64-row tiles.
// Computes S^T[n][g] = mfma(K, Q^T) so softmax state lives per-lane (g = l&15).
__global__ __launch_bounds__(256)
void flash_ca(const bf16* __restrict__ qlin, const bf16* __restrict__ kv, bf16* __restrict__ o)
{
  constexpr int LDK = 72;
  __shared__ bf16 Qs[64 * LDK], Ks[64 * LDK], Vs[64 * LDK];
  const int bb = blockIdx.x / 12, h = blockIdx.x % 12;
  const int t = threadIdx.x, lane = t & 63, wid = t >> 6;
  const int q = lane >> 4, l15 = lane & 15;
#pragma unroll
  for (int i = 0; i < 2; i++) {
    int c = i * 256 + t; int row = c >> 3, off = (c & 7) * 8;
    int4 v = *(const int4*)(qlin + (long)(bb * 64 + row) * 768 + h * 64 + off);
    *(int4*)(Qs + row * LDK + off) = v;
  }
  __syncthreads();
  bf16x8 bq[2];
#pragma unroll
  for (int kk = 0; kk < 2; kk++) bq[kk] = *(const bf16x8*)(Qs + (wid * 16 + l15) * LDK + kk * 32 + q * 8);

  float mrun = -INFINITY, lrun = 0.0f;
  f32x4 od[4] = {};

  for (int n0 = 0; n0 < 4096; n0 += 64) {
    __syncthreads();
#pragma unroll
    for (int i = 0; i < 2; i++) {
      int c = i * 256 + t; int row = c >> 3, off = (c & 7) * 8;
      const bf16* base = kv + (long)(bb * 4096 + n0 + row) * 1536 + h * 64 + off;
      int4 kvv = *(const int4*)base;
      *(int4*)(Ks + row * LDK + off) = kvv;
      int4 vvv = *(const int4*)(base + 768);
      *(int4*)(Vs + row * LDK + off) = vvv;
    }
    __syncthreads();
    f32x4 accs[4] = {};
#pragma unroll
    for (int kk = 0; kk < 2; kk++)
#pragma unroll
      for (int nf = 0; nf < 4; nf++) {
        bf16x8 ak = *(const bf16x8*)(Ks + (nf * 16 + l15) * LDK + kk * 32 + q * 8);
        accs[nf] = __builtin_amdgcn_mfma_f32_16x16x32_bf16(ak, bq[kk], accs[nf], 0, 0, 0);
      }
    // online softmax; this lane owns g = wid*16 + l15, 16 n-values
    float p[4][4];
    float tmax = -INFINITY;
#pragma unroll
    for (int nf = 0; nf < 4; nf++)
#pragma unroll
      for (int r = 0; r < 4; r++) { p[nf][r] = accs[nf][r] * 0.125f; tmax = fmaxf(tmax, p[nf][r]); }
    tmax = fmaxf(tmax, __shfl_xor(tmax, 16, 64));
    tmax = fmaxf(tmax, __shfl_xor(tmax, 32, 64));
    float mnew = fmaxf(mrun, tmax);
    float alpha = __expf(mrun - mnew);
    mrun = mnew;
    float psum = 0.f;
    unsigned plo[4], phi[4];
#pragma unroll
    for (int nf = 0; nf < 4; nf++) {
#pragma unroll
      for (int r = 0; r < 4; r++) { p[nf][r] = __expf(p[nf][r] - mnew); psum += p[nf][r]; }
      plo[nf] = pack2bf(p[nf][0], p[nf][1]);
      phi[nf] = pack2bf(p[nf][2], p[nf][3]);
    }
    psum += __shfl_xor(psum, 16, 64);
    psum += __shfl_xor(psum, 32, 64);
    lrun = lrun * alpha + psum;
#pragma unroll
    for (int r = 0; r < 4; r++) {
      float ar = __shfl(alpha, q * 4 + r, 64);
#pragma unroll
      for (int df = 0; df < 4; df++) od[df][r] *= ar;
    }
    // PV: A-frag P[g=l15][n-chunk] built by half-wave shuffles from S^T acc
    int src0 = ((q & 1) * 2) * 16 + l15;
    int src1 = src0 + 16;
    bool hi = (q >> 1);
#pragma unroll
    for (int c = 0; c < 2; c++) {
      unsigned x0 = __shfl(plo[2 * c], src0, 64), x1 = __shfl(phi[2 * c], src0, 64);
      unsigned x2 = __shfl(plo[2 * c], src1, 64), x3 = __shfl(phi[2 * c], src1, 64);
      unsigned y0 = __shfl(plo[2 * c + 1], src0, 64), y1 = __shfl(phi[2 * c + 1], src0, 64);
      unsigned y2 = __shfl(plo[2 * c + 1], src1, 64), y3 = __shfl(phi[2 * c + 1], src1, 64);
      union { unsigned u[4]; bf16x8 v; } cv;
      cv.u[0] = hi ? y0 : x0; cv.u[1] = hi ? y1 : x1; cv.u[2] = hi ? y2 : x2; cv.u[3] = hi ? y3 : x3;
#pragma unroll
      for (int df = 0; df < 4; df++) {
        union { unsigned short s[8]; bf16x8 v; } vb;
#pragma unroll
        for (int j = 0; j < 8; j++)
          vb.s[j] = ((const unsigned short*)Vs)[(c * 32 + q * 8 + j) * LDK + df * 16 + l15];
        od[df] = __builtin_amdgcn_mfma_f32_16x16x32_bf16(cv.v, vb.v, od[df], 0, 0, 0);
      }
    }
  }
  float linv = 1.0f / lrun;
#pragma unroll
  for (int r = 0; r < 4; r++) {
    float li = __shfl(linv, q * 4 + r, 64);
    int g = wid * 16 + q * 4 + r;
#pragma unroll
    for (int df = 0; df < 4; df++)
      o[(long)(bb * 64 + g) * 768 + h * 64 + df * 16 + l15] = __float2bfloat16(od[df][r] * li);
  }
}

// ---------------------------------------------------------------- assign: argmax over groups
__global__ __launch_bounds__(256)
void assign_argmax(const bf16* __restrict__ aq, const bf16* __restrict__ kvas,
                   int* __restrict__ idx, int* __restrict__ counts)
{
  __shared__ bf16 aqs[64 * 32];
  __shared__ bf16 aks[256 * 32];
  __shared__ int hist[64];
  const int b = blockIdx.y;
  const int n0 = blockIdx.x * 256;
  const int t = threadIdx.x, lane = t & 63, wid = t >> 6;
  const int q = lane >> 4, l15 = lane & 15;
  const int wn = wid * 64;
  if (t < 64) hist[t] = 0;
  f32x4 acc[4][4] = {};
  for (int k0 = 0; k0 < 768; k0 += 32) {
    __syncthreads();
    { int c16 = t; int row = c16 >> 2, ko = (c16 & 3) * 8;
      gload_lds16(aq + (long)(b * 64 + row) * 768 + k0 + ko, (char*)aqs + c16 * 16); }
#pragma unroll
    for (int i = 0; i < 4; i++) {
      int c16 = i * 256 + t; int row = c16 >> 2, ko = (c16 & 3) * 8;
      gload_lds16(kvas + (long)(b * 4096 + n0 + row) * 1536 + k0 + ko, (char*)aks + c16 * 16);
    }
    __syncthreads();
    bf16x8 af[4], bfr[4];
#pragma unroll
    for (int gf = 0; gf < 4; gf++) af[gf] = *(const bf16x8*)(aqs + (gf * 16 + l15) * 32 + q * 8);
#pragma unroll
    for (int nf = 0; nf < 4; nf++) bfr[nf] = *(const bf16x8*)(aks + (wn + nf * 16 + l15) * 32 + q * 8);
#pragma unroll
    for (int gf = 0; gf < 4; gf++)
#pragma unroll
      for (int nf = 0; nf < 4; nf++)
        acc[gf][nf] = __builtin_amdgcn_mfma_f32_16x16x32_bf16(af[gf], bfr[nf], acc[gf][nf], 0, 0, 0);
  }
#pragma unroll
  for (int nf = 0; nf < 4; nf++) {
    float mv = -INFINITY; int mi = 0;
#pragma unroll
    for (int gf = 0; gf < 4; gf++)
#pragma unroll
      for (int r = 0; r < 4; r++) {
        float v = acc[gf][nf][r]; int g = gf * 16 + q * 4 + r;
        if (v > mv) { mv = v; mi = g; }
      }
#pragma unroll
    for (int off = 16; off < 64; off <<= 1) {
      float ov = __shfl_xor(mv, off, 64);
      int oi = __shfl_xor(mi, off, 64);
      if (ov > mv || (ov == mv && oi < mi)) { mv = ov; mi = oi; }
    }
    if (q == 0) {
      idx[b * 4096 + n0 + wn + nf * 16 + l15] = mi;
      atomicAdd(&hist[mi], 1);
    }
  }
  __syncthreads();
  if (t < 64) atomicAdd(&counts[b * 64 + t], hist[t]);
}

// ---------------------------------------------------------------- scatter av rows by group
__global__ __launch_bounds__(256)
void scatter_av(const bf16* __restrict__ kvas, const int* __restrict__ idx, float* __restrict__ nx_part)
{
  __shared__ float acc[64 * 256];
  const int cc = blockIdx.x, ns = blockIdx.y, b = blockIdx.z;
  const int t = threadIdx.x;
  for (int i = t; i < 64 * 256; i += 256) acc[i] = 0.f;
  __syncthreads();
  const bf16* av = kvas + (long)b * 4096 * 1536 + 768 + cc * 256 + t;
  const int* ib = idx + b * 4096 + ns * 1024;
  for (int n = 0; n < 1024; n += 8) {
    int g[8]; float v[8];
#pragma unroll
    for (int u = 0; u < 8; u++) {
      g[u] = ib[n + u];
      v[u] = __bfloat162float(av[(long)(ns * 1024 + n + u) * 1536]);
    }
#pragma unroll
    for (int u = 0; u < 8; u++) acc[g[u] * 256 + t] += v[u];
  }
  __syncthreads();
  float* dst = nx_part + ((long)ns * 2048 + b * 64) * 768 + cc * 256 + t;
  for (int gg = 0; gg < 64; gg++) dst[(long)gg * 768] = acc[gg * 256 + t];
}

__global__ void scale_nx(const float* __restrict__ nx_part, const int* __restrict__ counts, bf16* __restrict__ outb)
{
  int i = blockIdx.x * 256 + threadIdx.x;
  int row = i / 768;
  float s = nx_part[i] + nx_part[i + 1572864] + nx_part[i + 2 * 1572864] + nx_part[i + 3 * 1572864];
  outb[i] = __float2bfloat16(s * (1.0f / ((float)counts[row] + 1.0f)));
}

// ---------------------------------------------------------------- launcher
extern "C" void kernel_launch(void* const* d_in, const int* in_sizes, int n_in,
                              void* d_out, int out_size, void* d_ws, size_t ws_size,
                              hipStream_t stream)
{
  const float* x         = (const float*)d_in[0];
  const float* gtok      = (const float*)d_in[1];
  const float* ln_tok_g  = (const float*)d_in[2];
  const float* ln_tok_b  = (const float*)d_in[3];
  const float* ln_x_g    = (const float*)d_in[4];
  const float* ln_x_b    = (const float*)d_in[5];
  const float* inter_w1  = (const float*)d_in[6];
  const float* inter_b1  = (const float*)d_in[7];
  const float* inter_w2  = (const float*)d_in[8];
  const float* inter_b2  = (const float*)d_in[9];
  const float* ln_pt_g   = (const float*)d_in[10];
  const float* ln_pt_b   = (const float*)d_in[11];
  const float* ca_qw = (const float*)d_in[12]; const float* ca_qb = (const float*)d_in[13];
  const float* ca_kw = (const float*)d_in[14]; const float* ca_kb = (const float*)d_in[15];
  const float* ca_vw = (const float*)d_in[16]; const float* ca_vb = (const float*)d_in[17];
  const float* ca_pw = (const float*)d_in[18]; const float* ca_pb = (const float*)d_in[19];
  const float* ca_ln2_g = (const float*)d_in[20]; const float* ca_ln2_b = (const float*)d_in[21];
  const float* ca_m1w = (const float*)d_in[22]; const float* ca_m1b = (const float*)d_in[23];
  const float* ca_m2w = (const float*)d_in[24]; const float* ca_m2b = (const float*)d_in[25];
  const float* ca_lnp_g = (const float*)d_in[26]; const float* ca_lnp_b = (const float*)d_in[27];
  const float* as_qw = (const float*)d_in[28]; const float* as_qb = (const float*)d_in[29];
  const float* as_kw = (const float*)d_in[30]; const float* as_kb = (const float*)d_in[31];
  const float* as_vw = (const float*)d_in[32]; const float* as_vb = (const float*)d_in[33];
  const float* as_pw = (const float*)d_in[34]; const float* as_pb = (const float*)d_in[35];
  const float* ln_nx_g = (const float*)d_in[36]; const float* ln_nx_b = (const float*)d_in[37];
  const float* mc_w1 = (const float*)d_in[38]; const float* mc_b1 = (const float*)d_in[39];
  const float* mc_w2 = (const float*)d_in[40]; const float* mc_b2 = (const float*)d_in[41];

  char* p = (char*)d_ws;
  auto alloc = [&](size_t bytes) -> char* {
    char* r = p; p += (bytes + 255) & ~(size_t)255; return r;
  };
  bf16* xn     = (bf16*)alloc(131072ll * 768 * 2);
  bf16* kvb    = (bf16*)alloc(131072ll * 1536 * 2);
  bf16* w_kvca = (bf16*)alloc(1536ll * 768 * 2);
  bf16* w_kvas = (bf16*)alloc(1536ll * 768 * 2);
  bf16* w_caq  = (bf16*)alloc(768ll * 768 * 2);
  bf16* w_cap  = (bf16*)alloc(768ll * 768 * 2);
  bf16* w_asq  = (bf16*)alloc(768ll * 768 * 2);
  bf16* w_asp  = (bf16*)alloc(768ll * 768 * 2);
  bf16* w_cam1 = (bf16*)alloc(3072ll * 768 * 2);
  bf16* w_cam2 = (bf16*)alloc(768ll * 3072 * 2);
  bf16* w_mc1  = (bf16*)alloc(3072ll * 768 * 2);
  bf16* w_mc2  = (bf16*)alloc(768ll * 3072 * 2);
  bf16* w_i1   = (bf16*)alloc(384ll * 128 * 2);
  bf16* w_i2   = (bf16*)alloc(64ll * 384 * 2);
  float* kvbias = (float*)alloc(3072 * 4);
  float* gt_f   = (float*)alloc(4096ll * 768 * 4);
  bf16* gtT    = (bf16*)alloc(32ll * 768 * 128 * 2);
  bf16* h1     = (bf16*)alloc(32ll * 768 * 384 * 2);
  float* pgt_pre = (float*)alloc(2048ll * 768 * 4);
  float* pgt_f  = (float*)alloc(2048ll * 768 * 4);
  bf16* pgt_b  = (bf16*)alloc(2048ll * 768 * 2);
  bf16* qlin   = (bf16*)alloc(2048ll * 768 * 2);
  bf16* ob     = (bf16*)alloc(2048ll * 768 * 2);
  float* y_f    = (float*)alloc(2048ll * 768 * 4);
  bf16* yln    = (bf16*)alloc(2048ll * 768 * 2);
  bf16* mlph   = (bf16*)alloc(2048ll * 3072 * 2);
  float* y2     = (float*)alloc(2048ll * 768 * 4);
  float* pgt2_f = (float*)alloc(2048ll * 768 * 4);
  bf16* pgt2_b = (bf16*)alloc(2048ll * 768 * 2);
  bf16* aqb    = (bf16*)alloc(2048ll * 768 * 2);
  int* idx     = (int*)alloc(32ll * 4096 * 4);
  int* counts  = (int*)alloc(2048 * 4);
  float* nx_part = (float*)alloc(4ll * 2048 * 768 * 4);
  bf16* nxs    = (bf16*)alloc(2048ll * 768 * 2);
  float* newx   = (float*)alloc(2048ll * 768 * 4);
  bf16* nxln   = (bf16*)alloc(2048ll * 768 * 2);
  bf16* mch    = (bf16*)alloc(2048ll * 3072 * 2);

  // ---- weight prep (bf16, transposed to [N,K]) ----
  TTab tab = {{
    {ca_kw,  w_kvca,             768, 768},
    {ca_vw,  w_kvca + 768 * 768, 768, 768},
    {as_kw,  w_kvas,             768, 768},
    {as_vw,  w_kvas + 768 * 768, 768, 768},
    {ca_qw,  w_caq,  768, 768},
    {ca_pw,  w_cap,  768, 768},
    {as_qw,  w_asq,  768, 768},
    {as_pw,  w_asp,  768, 768},
    {ca_m1w, w_cam1, 768, 3072},
    {ca_m2w, w_cam2, 3072, 768},
    {mc_w1,  w_mc1,  768, 3072},
    {mc_w2,  w_mc2,  3072, 768},
    {inter_w1, w_i1, 128, 384},
    {inter_w2, w_i2, 384, 64},
  }};
  transpose_many<<<3474, 256, 0, stream>>>(tab);
  concat_bias<<<12, 256, 0, stream>>>(ca_kb, ca_vb, as_kb, as_vb, kvbias);
  hipMemsetAsync(counts, 0, 2048 * sizeof(int), stream);

  // ---- norms ----
  ln768<false, true><<<131072, 256, 0, stream>>>(x, ln_x_g, ln_x_b, nullptr, xn);
  ln768<true, false><<<4096, 256, 0, stream>>>(gtok, ln_tok_g, ln_tok_b, gt_f, nullptr);

  // ---- big GEMM 1: k|v = xn @ [ca_kw|ca_vw] ----
  gemm_bt<128, 128, false, false, true, false, bf16><<<dim3(12, 1024, 1), 256, 0, stream>>>(
      xn, w_kvca, kvb, kvbias, nullptr, 131072, 1536, 768, 0, 0, 1536);

  // ---- group-token MLP over token dim ----
  transpose_batched<<<dim3(12, 2, 32), 256, 0, stream>>>(gt_f, gtT, 128, 768, 128ll * 768, 768ll * 128);
  gemm_bt<64, 64, true, false, true, false, bf16><<<dim3(6, 12, 32), 256, 0, stream>>>(
      gtT, w_i1, h1, inter_b1, nullptr, 768, 384, 128, 768ll * 128, 768ll * 384, 384);
  gemm_bt<64, 64, false, true, true, false, float><<<dim3(1, 12, 32), 256, 0, stream>>>(
      h1, w_i2, pgt_pre, inter_b2, nullptr, 768, 64, 384, 768ll * 384, 64ll * 768, 768);
  ln768<true, true><<<2048, 256, 0, stream>>>(pgt_pre, ln_pt_g, ln_pt_b, pgt_f, pgt_b);

  // ---- cross-attention block ----
  gemm_bt<64, 64, false, false, true, false, bf16><<<dim3(12, 32, 1), 256, 0, stream>>>(
      pgt_b, w_caq, qlin, ca_qb, nullptr, 2048, 768, 768, 0, 0, 768);
  flash_ca<<<384, 256, 0, stream>>>(qlin, kvb, ob);
  gemm_bt<64, 64, false, false, true, true, float><<<dim3(12, 32, 1), 256, 0, stream>>>(
      ob, w_cap, y_f, ca_pb, pgt_f, 2048, 768, 768, 0, 0, 768);
  ln768<false, true><<<2048, 256, 0, stream>>>(y_f, ca_ln2_g, ca_ln2_b, nullptr, yln);
  gemm_bt<128, 128, true, false, true, false, bf16><<<dim3(24, 16, 1), 256, 0, stream>>>(
      yln, w_cam1, mlph, ca_m1b, nullptr, 2048, 3072, 768, 0, 0, 3072);
  gemm_bt<64, 64, false, false, true, true, float><<<dim3(12, 32, 1), 256, 0, stream>>>(
      mlph, w_cam2, y2, ca_m2b, y_f, 2048, 768, 3072, 0, 0, 768);
  ln768<true, true><<<2048, 256, 0, stream>>>(y2, ca_lnp_g, ca_lnp_b, pgt2_f, pgt2_b);

  // ---- assign attention ----
  gemm_bt<64, 64, false, false, true, false, bf16><<<dim3(12, 32, 1), 256, 0, stream>>>(
      pgt2_b, w_asq, aqb, as_qb, nullptr, 2048, 768, 768, 0, 0, 768);
  gemm_bt<128, 128, false, false, true, false, bf16><<<dim3(12, 1024, 1), 256, 0, stream>>>(
      xn, w_kvas, kvb, kvbias + 1536, nullptr, 131072, 1536, 768, 0, 0, 1536);
  assign_argmax<<<dim3(16, 32, 1), 256, 0, stream>>>(aqb, kvb, idx, counts);
  scatter_av<<<dim3(3, 4, 32), 256, 0, stream>>>(kvb, idx, nx_part);
  scale_nx<<<6144, 256, 0, stream>>>(nx_part, counts, nxs);
  gemm_bt<64, 64, false, false, true, true, float><<<dim3(12, 32, 1), 256, 0, stream>>>(
      nxs, w_asp, newx, as_pb, pgt2_f, 2048, 768, 768, 0, 0, 768);

  // ---- channel MLP ----
  ln768<false, true><<<2048, 256, 0, stream>>>(newx, ln_nx_g, ln_nx_b, nullptr, nxln);
  gemm_bt<128, 128, true, false, true, false, bf16><<<dim3(24, 16, 1), 256, 0, stream>>>(
      nxln, w_mc1, mch, mc_b1, nullptr, 2048, 3072, 768, 0, 0, 3072);
  gemm_bt<64, 64, false, false, true, true, float><<<dim3(12, 32, 1), 256, 0, stream>>>(
      mch, w_mc2, (float*)d_out, mc_b2, newx, 2048, 768, 3072, 0, 0, 768);
}